// Round 4
// baseline (1018.113 us; speedup 1.0000x reference)
//
#include <hip/hip_runtime.h>
#include <math.h>

typedef unsigned short ushort_t;
typedef unsigned int uint_t;

// Problem constants (fixed by the reference)
#define BB 16
#define TT 2000
#define DENC 512
#define VV 1024
#define EE 256
#define PP 640
#define PPAD 768
#define MM (BB * TT)   // 32000 rows

typedef __attribute__((ext_vector_type(8))) short bf16x8;
typedef __attribute__((ext_vector_type(4))) float f32x4;

// ---------------------------------------------------------------------------
// helpers
// ---------------------------------------------------------------------------
__device__ __forceinline__ ushort_t f2bf(float x) {
    union { float f; uint_t u; } v; v.f = x;
    uint_t r = v.u + 0x7fffu + ((v.u >> 16) & 1u);   // RTNE
    return (ushort_t)(r >> 16);
}

__device__ __forceinline__ void async_ld16(const ushort_t* g, ushort_t* l) {
    __builtin_amdgcn_global_load_lds(
        (const __attribute__((address_space(1))) void*)g,
        (__attribute__((address_space(3))) void*)l, 16, 0, 0);
}

// ---------------------------------------------------------------------------
// 1) prep kernel: encoder cvt | 6 transposes | emb cvt | WT pad-zero |
//    padded biases + lens | parallel ctx scan.
// ---------------------------------------------------------------------------
#define NB_CVT  16000                    // MM*DENC/1024
#define B_TR    16000
#define NB_TR   3152
#define B_EMB   (B_TR + NB_TR)           // 19152
#define NB_EMB  256
#define B_PAD   (B_EMB + NB_EMB)         // 19408
#define NB_PAD  34
#define B_MISC  (B_PAD + NB_PAD)         // 19442
#define B_CTX   (B_MISC + 1)             // 19443
#define NB_PREP (B_CTX + BB)             // 19459

__global__ __launch_bounds__(256) void prep_kernel(
    const float* __restrict__ encoder_out, const int* __restrict__ features_len,
    const int* __restrict__ targets,
    const float* __restrict__ W_enc, const float* __restrict__ W_p1,
    const float* __restrict__ W_p2,  const float* __restrict__ W_po,
    const float* __restrict__ W_j1,  const float* __restrict__ W_j2,
    const float* __restrict__ b_p1,  const float* __restrict__ b_p2,
    const float* __restrict__ b_j1,  const float* __restrict__ emb,
    ushort_t* __restrict__ Abuf,
    ushort_t* __restrict__ WTenc, ushort_t* __restrict__ WTp1,
    ushort_t* __restrict__ WTp2,  ushort_t* __restrict__ WTpo,
    ushort_t* __restrict__ WTj1,  ushort_t* __restrict__ WTj2,
    ushort_t* __restrict__ embB,
    float* __restrict__ bp1p, float* __restrict__ bp2p, float* __restrict__ bj1p,
    int* __restrict__ ctx0, int* __restrict__ ctx1, float* __restrict__ out_lens) {
    const int blk = blockIdx.x;
    const int tid = threadIdx.x;

    if (blk < NB_CVT) {                       // encoder_out fp32 -> bf16 Abuf
        size_t i = ((size_t)blk * 256 + tid) * 4;
        float4 v = *(const float4*)(encoder_out + i);
        ushort_t o[4] = {f2bf(v.x), f2bf(v.y), f2bf(v.z), f2bf(v.w)};
        *(uint2*)(Abuf + i) = *(uint2*)o;
        return;
    }
    if (blk < B_EMB) {                        // weight transposes (real regions)
        int t = blk - B_TR;
        const float* W; ushort_t* WT; int K, N, base;
        if (t < 512)       { W = W_enc; WT = WTenc; K = 512;  N = 1024; base = 0; }
        else if (t < 832)  { W = W_p1;  WT = WTp1;  K = 512;  N = 640;  base = 512; }
        else if (t < 1232) { W = W_p2;  WT = WTp2;  K = 640;  N = 640;  base = 832; }
        else if (t < 1872) { W = W_po;  WT = WTpo;  K = 640;  N = 1024; base = 1232; }
        else if (t < 2512) { W = W_j1;  WT = WTj1;  K = 1024; N = 640;  base = 1872; }
        else               { W = W_j2;  WT = WTj2;  K = 640;  N = 1024; base = 2512; }
        t -= base;
        const int tilesN = N / 32;
        const int n0 = (t % tilesN) * 32, k0 = (t / tilesN) * 32;
        __shared__ float sm[32][33];
        const int tx = tid & 31, ty0 = tid >> 5;
        #pragma unroll
        for (int i = 0; i < 4; ++i) {
            int ty = ty0 + i * 8;
            sm[ty][tx] = W[(size_t)(k0 + ty) * N + n0 + tx];
        }
        __syncthreads();
        #pragma unroll
        for (int i = 0; i < 4; ++i) {
            int ty = ty0 + i * 8;
            WT[(size_t)(n0 + ty) * K + k0 + tx] = f2bf(sm[tx][ty]);
        }
        return;
    }
    if (blk < B_PAD) {                        // emb fp32 -> bf16 table (1024x256)
        int t = blk - B_EMB;
        size_t i = ((size_t)t * 256 + tid) * 4;
        float4 v = *(const float4*)(emb + i);
        ushort_t o[4] = {f2bf(v.x), f2bf(v.y), f2bf(v.z), f2bf(v.w)};
        *(uint2*)(embB + i) = *(uint2*)o;
        return;
    }
    if (blk < B_MISC) {                       // zero pad rows of padded WTs
        int t = blk - B_PAD;
        ushort_t* dst; size_t off;
        if (t < 8)       { dst = WTp1 + (size_t)640 * 512;  off = (size_t)t * 8192; }
        else if (t < 18) { dst = WTp2 + (size_t)640 * 640;  off = (size_t)(t - 8) * 8192; }
        else             { dst = WTj1 + (size_t)640 * 1024; off = (size_t)(t - 18) * 8192; }
        uint4 z = {0, 0, 0, 0};
        ushort_t* p = dst + off + tid * 32;
        #pragma unroll
        for (int i = 0; i < 4; ++i) *(uint4*)(p + i * 8) = z;
        return;
    }
    if (blk < B_CTX) {                        // padded biases + lens
        for (int t = tid; t < PPAD; t += 256) {
            bp1p[t] = (t < PP) ? b_p1[t] : 0.f;
            bp2p[t] = (t < PP) ? b_p2[t] : 0.f;
            bj1p[t] = (t < PP) ? b_j1[t] : 0.f;
        }
        if (tid < BB) out_lens[tid] = (float)features_len[tid];
        return;
    }
    {                                          // parallel ctx scan, one block/row
        const int b = blk - B_CTX;
        __shared__ int tg[2048];
        __shared__ int cc[2048];
        __shared__ int wl[4];
        const int* row = targets + b * TT;
        for (int t = tid; t < 2048; t += 256) tg[t] = (t < TT) ? row[t] : 0;
        __syncthreads();
        const int lane = tid & 63, wv = tid >> 6;
        const int base = tid * 8;
        int lastIdx = -1;
        #pragma unroll
        for (int i = 0; i < 8; ++i) { if (tg[base + i] != 0) lastIdx = base + i; }
        int incl = lastIdx;
        #pragma unroll
        for (int o = 1; o < 64; o <<= 1) {
            int u = __shfl_up(incl, o, 64);
            if (lane >= o) incl = max(incl, u);
        }
        if (lane == 63) wl[wv] = incl;
        __syncthreads();
        int excl = -1;
        for (int w = 0; w < 4; ++w) if (w < wv) excl = max(excl, wl[w]);
        int u = __shfl_up(incl, 1, 64);
        if (lane > 0) excl = max(excl, u);
        int cur = excl;
        #pragma unroll
        for (int i = 0; i < 8; ++i) {
            int idx = base + i;
            cc[idx] = (cur >= 0) ? tg[cur] : 0;
            if (tg[idx] != 0) cur = idx;
        }
        __syncthreads();
        for (int t = tid; t < TT; t += 256) {
            ctx0[b * TT + t] = cc[t];
            ctx1[b * TT + t] = t ? cc[t - 1] : 0;
        }
    }
}

// ---------------------------------------------------------------------------
// 2) 256x256 8-phase GEMM (kept for the three N=768 hidden-layer GEMMs)
// ---------------------------------------------------------------------------
__device__ __forceinline__ void stage_half(const ushort_t* __restrict__ X, int xBase,
                                           int lda, int kt, int h, ushort_t* region,
                                           int tid) {
    const int wb = tid & ~63;
    #pragma unroll
    for (int s = 0; s < 2; ++s) {
        const int c  = s * 512 + tid;
        const int rH = c >> 3;
        const int k8 = (c & 7) ^ (rH & 7);
        const ushort_t* g = X + (size_t)(xBase + h * 128 + rH) * lda + kt + k8 * 8;
        ushort_t* l = region + ((size_t)(h * 1024 + s * 512 + wb)) * 8;
        async_ld16(g, l);
    }
}

__device__ __forceinline__ void stage_g(const ushort_t* b0, const ushort_t* b1,
                                        int kt, int h, int s, ushort_t* region, int tid) {
    const int wb = tid & ~63;
    const int c  = s * 512 + tid;
    const int rH = c >> 3;
    const int k8 = (c & 7) ^ (rH & 7);
    const ushort_t* base = (kt < 256) ? (b0 + kt) : (b1 + (kt - 256));
    async_ld16(base + k8 * 8, region + ((size_t)(h * 1024 + s * 512 + wb)) * 8);
}

template<int OMODE, bool GATHER>   // OMODE 1: bf16 tanh out (only mode used now)
__global__ __launch_bounds__(512, 2) void gemm256_kernel(
    const ushort_t* __restrict__ A, const ushort_t* __restrict__ BT,
    const float* __restrict__ bias, void* __restrict__ Cout,
    const ushort_t* __restrict__ embB, const int* __restrict__ ctx0,
    const int* __restrict__ ctx1,
    int N, int K, int lda, int ldc, int GX) {
    extern __shared__ __align__(16) ushort_t smem[];   // 131072 bytes
    ushort_t* A0 = smem;
    ushort_t* B0 = smem + 16384;
    ushort_t* A1 = smem + 32768;
    ushort_t* B1 = smem + 49152;

    const int nwg = gridDim.x;
    const int orig = blockIdx.x;
    const int q8 = nwg >> 3, r8 = nwg & 7;
    const int xcd = orig & 7, slot = orig >> 3;
    const int wgid = (xcd < r8 ? xcd * (q8 + 1) : r8 * (q8 + 1) + (xcd - r8) * q8) + slot;
    const int bx = wgid % GX, by = wgid / GX;

    const int tid = threadIdx.x;
    const int lane = tid & 63;
    const int ln = lane & 15, quad = lane >> 4;
    const int wave = tid >> 6;
    const int wr = wave >> 2, wc = wave & 3;
    const int rowBase = by * 256, colBase = bx * 256;
    const int NT = K >> 6;

    const ushort_t* g0[2][2];
    const ushort_t* g1[2][2];
    if (GATHER) {
        #pragma unroll
        for (int h = 0; h < 2; ++h)
            #pragma unroll
            for (int s = 0; s < 2; ++s) {
                int rH = (s * 512 + tid) >> 3;
                int row = rowBase + h * 128 + rH;
                g0[h][s] = embB + (size_t)ctx0[row] * EE;
                g1[h][s] = embB + (size_t)ctx1[row] * EE;
            }
    }

    f32x4 acc[4][2][4] = {};

    if (GATHER) {
        stage_g(g0[0][0], g1[0][0], 0, 0, 0, A0, tid);
        stage_g(g0[0][1], g1[0][1], 0, 0, 1, A0, tid);
        stage_g(g0[1][0], g1[1][0], 0, 1, 0, A0, tid);
        stage_g(g0[1][1], g1[1][1], 0, 1, 1, A0, tid);
    } else {
        stage_half(A, rowBase, lda, 0, 0, A0, tid);
        stage_half(A, rowBase, lda, 0, 1, A0, tid);
    }
    stage_half(BT, colBase, K, 0,  0, B0, tid);
    stage_half(BT, colBase, K, 0,  1, B0, tid);
    stage_half(BT, colBase, K, 64, 0, B1, tid);
    stage_half(BT, colBase, K, 64, 1, B1, tid);
    asm volatile("s_waitcnt vmcnt(4)" ::: "memory");
    __builtin_amdgcn_s_barrier();

    for (int t = 0; t < NT; ++t) {
        const int cur = t & 1;
        const char* cA = (const char*)(cur ? A1 : A0);
        const char* cB = (const char*)(cur ? B1 : B0);
        ushort_t* oA  = cur ? A0 : A1;
        ushort_t* cBw = cur ? B1 : B0;
        const int ktA = (t + 1 < NT ? t + 1 : NT - 1) * 64;
        const int ktB = (t + 2 < NT ? t + 2 : NT - 1) * 64;

        bf16x8 bfr[4][2];
        #pragma unroll
        for (int q = 0; q < 4; ++q) {
            if (q == 0) {
                #pragma unroll
                for (int n = 0; n < 4; ++n)
                    #pragma unroll
                    for (int ks = 0; ks < 2; ++ks) {
                        int off = (wc * 64 + n * 16 + ln) * 128 + ks * 64 + quad * 16;
                        off ^= (ln & 7) << 4;
                        bfr[n][ks] = *(const bf16x8*)(cB + off);
                    }
            }
            bf16x8 afr[2][2];
            #pragma unroll
            for (int m = 0; m < 2; ++m)
                #pragma unroll
                for (int ks = 0; ks < 2; ++ks) {
                    int off = (wr * 128 + q * 32 + m * 16 + ln) * 128 + ks * 64 + quad * 16;
                    off ^= (ln & 7) << 4;
                    afr[m][ks] = *(const bf16x8*)(cA + off);
                }
            if (q == 0) {
                if (GATHER) { stage_g(g0[0][0], g1[0][0], ktA, 0, 0, oA, tid);
                              stage_g(g0[0][1], g1[0][1], ktA, 0, 1, oA, tid); }
                else        stage_half(A, rowBase, lda, ktA, 0, oA, tid);
            } else if (q == 1) {
                if (GATHER) { stage_g(g0[1][0], g1[1][0], ktA, 1, 0, oA, tid);
                              stage_g(g0[1][1], g1[1][1], ktA, 1, 1, oA, tid); }
                else        stage_half(A, rowBase, lda, ktA, 1, oA, tid);
            } else if (q == 2) {
                stage_half(BT, colBase, K, ktB, 0, cBw, tid);
            } else {
                stage_half(BT, colBase, K, ktB, 1, cBw, tid);
            }

            __builtin_amdgcn_s_barrier();
            __builtin_amdgcn_s_setprio(1);
            #pragma unroll
            for (int m = 0; m < 2; ++m)
                #pragma unroll
                for (int n = 0; n < 4; ++n)
                    #pragma unroll
                    for (int ks = 0; ks < 2; ++ks)
                        acc[q][m][n] = __builtin_amdgcn_mfma_f32_16x16x32_bf16(
                            afr[m][ks], bfr[n][ks], acc[q][m][n], 0, 0, 0);
            __builtin_amdgcn_s_setprio(0);
            if (q == 3)
                asm volatile("s_waitcnt vmcnt(4)" ::: "memory");
            __builtin_amdgcn_s_barrier();
        }
    }

    float bv[4];
    #pragma unroll
    for (int n = 0; n < 4; ++n) bv[n] = bias[colBase + wc * 64 + n * 16 + ln];

    #pragma unroll
    for (int q = 0; q < 4; ++q)
        #pragma unroll
        for (int m = 0; m < 2; ++m)
            #pragma unroll
            for (int rr = 0; rr < 4; ++rr) {
                const size_t row = (size_t)(rowBase + wr * 128 + q * 32 + m * 16 + quad * 4 + rr);
                #pragma unroll
                for (int n = 0; n < 4; ++n) {
                    const int col = colBase + wc * 64 + n * 16 + ln;
                    const size_t idx = row * (size_t)ldc + col;
                    float v = acc[q][m][n][rr] + bv[n];
                    ((ushort_t*)Cout)[idx] = f2bf(tanhf(v));
                }
            }
}

// ---------------------------------------------------------------------------
// 3) Fused GEMM + row log-softmax for the N=1024 output layers.
//    Tile 64 rows x 1024 cols (full N in-block -> lse from registers, final
//    log-probs written ONCE; no separate softmax pass).
//    512 thr = 8 waves, wave w owns 64 rows x cols [w*128, w*128+128).
//    BK=32 double-buffered LDS: A[64][32], B[1024][32] bf16, 4-chunk XOR
//    swizzle (pos ^= row&3, both-sides).  2-phase prefetch loop (T3 minimum).
//    SMODE 0: write log-probs only (joint out)
//    SMODE 1: + write raw fp32 (enc head -> encraw for the joint input)
//    SMODE 2: + sumOut = bf16(raw + rawIn) (pred out + fused joint input)
// ---------------------------------------------------------------------------
__device__ __forceinline__ void stage64(const ushort_t* __restrict__ A,
                                        const ushort_t* __restrict__ BT,
                                        int row0, int lda, int K, int kt,
                                        ushort_t* Ab, ushort_t* Bb, int tid) {
    const int wb = tid & ~63;
    #pragma unroll
    for (int s = 0; s < 8; ++s) {                 // B: 1024x32 = 4096 chunks
        const int c = s * 512 + tid;
        const int rB = c >> 2, p = c & 3;
        const int k8 = p ^ (rB & 3);              // source pre-swizzle
        async_ld16(BT + (size_t)rB * K + kt + k8 * 8, Bb + (s * 512 + wb) * 8);
    }
    if (tid < 256) {                              // A: 64x32 = 256 chunks
        const int rA = tid >> 2, p = tid & 3;
        const int k8 = p ^ (rA & 3);
        async_ld16(A + (size_t)(row0 + rA) * lda + kt + k8 * 8, Ab + wb * 8);
    }
}

template<int SMODE>
__global__ __launch_bounds__(512, 2) void gemm_sm_kernel(
    const ushort_t* __restrict__ A, const ushort_t* __restrict__ BT,
    const float* __restrict__ bias, float* __restrict__ outLP,
    float* __restrict__ rawBuf,            // SMODE1: raw out; SMODE2: raw in
    ushort_t* __restrict__ sumOut,         // SMODE2 only
    int K, int lda) {
    extern __shared__ __align__(16) ushort_t smem[];   // 143360 bytes
    ushort_t* Ab0 = smem;                   // 64*32 us = 4096 B
    ushort_t* Ab1 = smem + 2048;
    ushort_t* Bb0 = smem + 4096;            // 1024*32 us = 65536 B
    ushort_t* Bb1 = smem + 4096 + 32768;
    float* redmax = (float*)(smem + 4096 + 65536);   // [8][64]
    float* redsum = redmax + 512;                    // [8][64]

    const int tid = threadIdx.x;
    const int lane = tid & 63;
    const int ln = lane & 15, quad = lane >> 4;
    const int w = tid >> 6;
    const int row0 = blockIdx.x * 64;
    const int NT = K >> 5;

    f32x4 acc[4][8] = {};    // [i (row 16-group)][n (col 16-group)], rr in vec

    stage64(A, BT, row0, lda, K, 0, Ab0, Bb0, tid);
    asm volatile("s_waitcnt vmcnt(0)" ::: "memory");
    __builtin_amdgcn_s_barrier();

    for (int t = 0; t < NT; ++t) {
        const char* cAb = (const char*)((t & 1) ? Ab1 : Ab0);
        const char* cBb = (const char*)((t & 1) ? Bb1 : Bb0);
        if (t + 1 < NT)
            stage64(A, BT, row0, lda, K, (t + 1) << 5,
                    (t & 1) ? Ab0 : Ab1, (t & 1) ? Bb0 : Bb1, tid);

        bf16x8 a[4], b[8];
        #pragma unroll
        for (int i = 0; i < 4; ++i) {
            int row = i * 16 + ln;
            int off = row * 64 + ((quad ^ (row & 3)) << 4);
            a[i] = *(const bf16x8*)(cAb + off);
        }
        #pragma unroll
        for (int n = 0; n < 8; ++n) {
            int row = w * 128 + n * 16 + ln;
            int off = row * 64 + ((quad ^ (row & 3)) << 4);
            b[n] = *(const bf16x8*)(cBb + off);
        }
        __builtin_amdgcn_s_setprio(1);
        #pragma unroll
        for (int i = 0; i < 4; ++i)
            #pragma unroll
            for (int n = 0; n < 8; ++n)
                acc[i][n] = __builtin_amdgcn_mfma_f32_16x16x32_bf16(
                    a[i], b[n], acc[i][n], 0, 0, 0);
        __builtin_amdgcn_s_setprio(0);
        if (t + 1 < NT)
            asm volatile("s_waitcnt vmcnt(0)" ::: "memory");
        __builtin_amdgcn_s_barrier();
    }

    // ---- epilogue: bias, then in-register row log-softmax over N=1024 ----
    float bv[8];
    #pragma unroll
    for (int n = 0; n < 8; ++n) bv[n] = bias[w * 128 + n * 16 + ln];
    #pragma unroll
    for (int i = 0; i < 4; ++i)
        #pragma unroll
        for (int n = 0; n < 8; ++n)
            acc[i][n] += bv[n];

    // per-row partial max (wave covers 128 cols of each of its 64 rows)
    #pragma unroll
    for (int i = 0; i < 4; ++i)
        #pragma unroll
        for (int rr = 0; rr < 4; ++rr) {
            float m = acc[i][0][rr];
            #pragma unroll
            for (int n = 1; n < 8; ++n) m = fmaxf(m, acc[i][n][rr]);
            #pragma unroll
            for (int o = 1; o < 16; o <<= 1) m = fmaxf(m, __shfl_xor(m, o, 64));
            if (ln == 0) redmax[w * 64 + i * 16 + quad * 4 + rr] = m;
        }
    __syncthreads();

    float Mr[4][4];
    #pragma unroll
    for (int i = 0; i < 4; ++i)
        #pragma unroll
        for (int rr = 0; rr < 4; ++rr) {
            const int row = i * 16 + quad * 4 + rr;
            float m = redmax[row];
            #pragma unroll
            for (int ww = 1; ww < 8; ++ww) m = fmaxf(m, redmax[ww * 64 + row]);
            Mr[i][rr] = m;
            float s = 0.f;
            #pragma unroll
            for (int n = 0; n < 8; ++n) s += expf(acc[i][n][rr] - m);
            #pragma unroll
            for (int o = 1; o < 16; o <<= 1) s += __shfl_xor(s, o, 64);
            if (ln == 0) redsum[w * 64 + row] = s;
        }
    __syncthreads();

    #pragma unroll
    for (int i = 0; i < 4; ++i)
        #pragma unroll
        for (int rr = 0; rr < 4; ++rr) {
            const int row = i * 16 + quad * 4 + rr;
            float S = 0.f;
            #pragma unroll
            for (int ww = 0; ww < 8; ++ww) S += redsum[ww * 64 + row];
            const float lse = logf(S) + Mr[i][rr];
            const size_t gr = (size_t)(row0 + row) * VV;
            #pragma unroll
            for (int n = 0; n < 8; ++n) {
                const int col = w * 128 + n * 16 + ln;
                const float v = acc[i][n][rr];
                if (SMODE == 1) rawBuf[gr + col] = v;
                if (SMODE == 2) sumOut[gr + col] = f2bf(v + rawBuf[gr + col]);
                outLP[gr + col] = v - lse;
            }
        }
}

// ---------------------------------------------------------------------------
extern "C" void kernel_launch(void* const* d_in, const int* in_sizes, int n_in,
                              void* d_out, int out_size, void* d_ws, size_t ws_size,
                              hipStream_t stream) {
    const float* encoder_out  = (const float*)d_in[0];
    const int*   features_len = (const int*)  d_in[1];
    const int*   targets      = (const int*)  d_in[2];
    const float* W_enc = (const float*)d_in[3];
    const float* b_enc = (const float*)d_in[4];
    const float* emb   = (const float*)d_in[5];
    const float* W_p1  = (const float*)d_in[6];
    const float* b_p1  = (const float*)d_in[7];
    const float* W_p2  = (const float*)d_in[8];
    const float* b_p2  = (const float*)d_in[9];
    const float* W_po  = (const float*)d_in[10];
    const float* b_po  = (const float*)d_in[11];
    const float* W_j1  = (const float*)d_in[12];
    const float* b_j1  = (const float*)d_in[13];
    const float* W_j2  = (const float*)d_in[14];
    const float* b_j2  = (const float*)d_in[15];

    float* out = (float*)d_out;
    const size_t BTV = (size_t)MM * VV;
    float* out_logits = out;             // log_probs      [B,T,V]
    float* out_pred   = out + BTV;       // pred_log_probs [B,T,V]
    float* out_enc    = out + 2 * BTV;   // enc_log_probs  [B,T,V]
    float* out_lens   = out + 3 * BTV;   // enc_lens       [B]

    // ---- workspace layout (bytes), total ~270 MB ----
    char* ws = (char*)d_ws;
    int*      ctx0  = (int*)ws;                                             // 128,000
    int*      ctx1  = (int*)(ws + 128000);                                  // 128,000
    size_t off = 256000;
    ushort_t* embB  = (ushort_t*)(ws + off); off += (size_t)VV * EE * 2;    //   524,288
    ushort_t* WTenc = (ushort_t*)(ws + off); off += (size_t)VV * DENC * 2;  // 1,048,576
    ushort_t* WTp1  = (ushort_t*)(ws + off); off += (size_t)PPAD * DENC * 2;//   786,432
    ushort_t* WTp2  = (ushort_t*)(ws + off); off += (size_t)PPAD * PP * 2;  //   983,040
    ushort_t* WTpo  = (ushort_t*)(ws + off); off += (size_t)VV * PP * 2;    // 1,310,720
    ushort_t* WTj1  = (ushort_t*)(ws + off); off += (size_t)PPAD * VV * 2;  // 1,572,864
    ushort_t* WTj2  = (ushort_t*)(ws + off); off += (size_t)VV * PP * 2;    // 1,310,720
    float*    bp1p  = (float*)(ws + off); off += PPAD * 4;                  //     3,072
    float*    bp2p  = (float*)(ws + off); off += PPAD * 4;                  //     3,072
    float*    bj1p  = (float*)(ws + off); off += PPAD * 4;                  //     3,072
    ushort_t* h1    = (ushort_t*)(ws + off); off += (size_t)MM * PPAD * 2;  // 49,152,000
    ushort_t* Abuf  = (ushort_t*)(ws + off); off += (size_t)MM * DENC * 2;  // 32,768,000
    ushort_t* h2    = (ushort_t*)(ws + off); off += (size_t)MM * PPAD * 2;  // 49,152,000
    float*    encraw= (float*)(ws + off);                                   //131,072,000
    ushort_t* sumb  = h1;   // aliases h1 + head of Abuf (both dead at that point)

    // dynamic LDS caps (host-side, graph-safe)
    hipFuncSetAttribute((const void*)&gemm256_kernel<1, true>,
                        hipFuncAttributeMaxDynamicSharedMemorySize, 131072);
    hipFuncSetAttribute((const void*)&gemm256_kernel<1, false>,
                        hipFuncAttributeMaxDynamicSharedMemorySize, 131072);
    hipFuncSetAttribute((const void*)&gemm_sm_kernel<0>,
                        hipFuncAttributeMaxDynamicSharedMemorySize, 143360);
    hipFuncSetAttribute((const void*)&gemm_sm_kernel<1>,
                        hipFuncAttributeMaxDynamicSharedMemorySize, 143360);
    hipFuncSetAttribute((const void*)&gemm_sm_kernel<2>,
                        hipFuncAttributeMaxDynamicSharedMemorySize, 143360);

    // 1) prep: cvt + transposes + emb cvt + pads + biases + lens + ctx
    prep_kernel<<<NB_PREP, 256, 0, stream>>>(
        encoder_out, features_len, targets,
        W_enc, W_p1, W_p2, W_po, W_j1, W_j2,
        b_p1, b_p2, b_j1, emb,
        Abuf, WTenc, WTp1, WTp2, WTpo, WTj1, WTj2,
        embB, bp1p, bp2p, bj1p, ctx0, ctx1, out_lens);

    // 2) predictor L1 (gather fused): h1 = tanh(emb[ctx] @ W_p1 + b_p1), N=768 pad
    gemm256_kernel<1, true><<<(PPAD/256)*(MM/256), 512, 131072, stream>>>(
        nullptr, WTp1, bp1p, h1, embB, ctx0, ctx1,
        PPAD, DENC, 0, PPAD, PPAD/256);

    // 3) encoder head + fused log-softmax: out_enc = logsm(Abuf@W_enc+b_enc),
    //    encraw = raw fp32 (for the joint input)
    gemm_sm_kernel<1><<<MM/64, 512, 143360, stream>>>(
        Abuf, WTenc, b_enc, out_enc, encraw, nullptr, DENC, DENC);

    // 4) predictor L2: h2 = tanh(h1 @ W_p2 + b_p2), K=640, lda=768, N=768 pad
    gemm256_kernel<1, false><<<(PPAD/256)*(MM/256), 512, 131072, stream>>>(
        h1, WTp2, bp2p, h2, nullptr, nullptr, nullptr,
        PPAD, PP, PPAD, PPAD, PPAD/256);

    // 5) predictor out + fused log-softmax + fused joint input:
    //    out_pred = logsm(h2@W_po+b_po), sumb = bf16(raw + encraw)
    gemm_sm_kernel<2><<<MM/64, 512, 143360, stream>>>(
        h2, WTpo, b_po, out_pred, encraw, sumb, PP, PPAD);

    // 6) joint hidden: h2' = tanh(sumb @ W_j1 + b_j1), K=1024, N=768 pad
    gemm256_kernel<1, false><<<(PPAD/256)*(MM/256), 512, 131072, stream>>>(
        sumb, WTj1, bj1p, h2, nullptr, nullptr, nullptr,
        PPAD, VV, VV, PPAD, PPAD/256);

    // 7) joint out + fused log-softmax: out_logits = logsm(h2'@W_j2+b_j2)
    gemm_sm_kernel<0><<<MM/64, 512, 143360, stream>>>(
        h2, WTj2, b_j2, out_logits, nullptr, nullptr, PP, PPAD);
}